// Round 11
// baseline (88.565 us; speedup 1.0000x reference)
//
#include <hip/hip_runtime.h>
#include <hip/hip_bf16.h>

typedef __attribute__((ext_vector_type(4))) float f32x4;
typedef __attribute__((ext_vector_type(8))) short s16x8;
typedef __attribute__((ext_vector_type(4))) short s16x4;
typedef __attribute__((ext_vector_type(4))) unsigned int u32x4;
typedef __attribute__((ext_vector_type(2))) unsigned int u32x2;

#define NODES 100000
#define SROW (NODES + 1)   // +1 zero row per slice: predication-free gathers
#define DIN 256
#define DOUT 128
#define NSLICE 2
#define SLICE_CH 64        // h_s[slice][SROW][64] bf16 = 12.8 MB/slice
#define EW 136             // epilogue LDS row stride (128 + 8 pad shorts)

static __device__ inline unsigned short f2bf(float f) {
    __hip_bfloat16 h = __float2bfloat16(f);
    return __builtin_bit_cast(unsigned short, h);
}
static __device__ inline float lo2f(unsigned int v) {  // low bf16 -> f32
    return __builtin_bit_cast(float, v << 16);
}
static __device__ inline float hi2f(unsigned int v) {  // high bf16 -> f32
    return __builtin_bit_cast(float, v & 0xffff0000u);
}

// lgkm-only barrier: LDS-write visibility without the vmcnt(0) drain that
// __syncthreads() forces. Global loads (into REGISTERS) stay in flight
// across it — the T4 counted-wait principle. Safe because inter-wave data
// exchange here goes only through LDS.
#define BARRIER_LGKM() asm volatile("s_waitcnt lgkmcnt(0)\ns_barrier" ::: "memory")

// ---------------- prep: W fp32 -> bf16 ; inv_deg ; zero rows ----------------
__global__ __launch_bounds__(256) void gcn_prep(const float* __restrict__ W,
                                                const int* __restrict__ ptr,
                                                unsigned short* __restrict__ wsW,
                                                float* __restrict__ inv_deg,
                                                unsigned short* __restrict__ h_s) {
    int t = blockIdx.x * 256 + threadIdx.x;
    if (t < DOUT * DIN) wsW[t] = f2bf(W[t]);
    if (t < NODES) {
        int d = ptr[t + 1] - ptr[t];
        inv_deg[t] = d > 0 ? 1.0f / (float)d : 0.0f;
    }
    if (t < NSLICE * SLICE_CH)  // zero row (node index NODES) of each slice
        h_s[(long)(t >> 6) * ((long)SROW * SLICE_CH) + (long)NODES * SLICE_CH + (t & 63)] = 0;
}

// ---------------- GEMM: h_s[slice][SROW][64] (bf16) = x @ W.T ---------------
// R10 diagnosis: __syncthreads' implicit vmcnt(0) drain nullified the dbuf
// prefetch (documented m97 stall) -> 44us. Fix: lgkm-only barriers (loads
// live in regs across barriers) + alternating staging reg sets R0/R1 so
// phase p = { issue LOAD(c+2) ; STAGE(c+1) ; COMPUTE(c) ; lgkm-barrier }.
// Each load gets ~2 full MFMA phases to land. Staging swizzle (T2 XOR,
// verified R9/R10): idx = row*64 + (c4 ^ ((row&7)<<3)). MFMA 16x16x32;
// C/D: col=lane&15, row=(lane>>4)*4+reg. Epilogue via padded LDS transpose.
__global__ __launch_bounds__(256) void gcn_gemm(const float* __restrict__ x,
                                                const unsigned short* __restrict__ wsW,
                                                unsigned short* __restrict__ h_s) {
    const int tid  = threadIdx.x;
    const int lane = tid & 63;
    const int wid  = tid >> 6;
    const int row0 = blockIdx.x * 128;   // max 781*128=99968 < NODES: no early exit
    const int lr = lane & 15;
    const int lg = lane >> 4;

    __shared__ char smem[65536];
    unsigned short* A0 = (unsigned short*)smem;          // 16 KB
    unsigned short* B0 = A0 + 8192;                      // 16 KB
    unsigned short* A1 = B0 + 8192;                      // 16 KB
    unsigned short* B1 = A1 + 8192;                      // 16 KB
    unsigned short* EP = (unsigned short*)smem;          // epilogue reuse (34.8 KB)

    const int st_sub = tid >> 4;        // staging row sub-index 0..15
    const int st_c4  = (tid & 15) * 4;  // staging col (element*4)

    f32x4 ar0[8], ar1[8];   // A stage regs, alternating sets
    u32x2 br0[8], br1[8];   // B stage regs, alternating sets

#define LOADA(AR, C) { _Pragma("unroll") for (int j = 0; j < 8; ++j) { \
        int grow = row0 + j * 16 + st_sub; \
        grow = grow < NODES ? grow : NODES - 1; /* clamp; never stored */ \
        AR[j] = *reinterpret_cast<const f32x4*>(x + (long)grow * DIN + (C) * 64 + st_c4); } }

#define LOADB(BR, C) { _Pragma("unroll") for (int j = 0; j < 8; ++j) { \
        const int out = j * 16 + st_sub; \
        BR[j] = *reinterpret_cast<const u32x2*>(wsW + out * DIN + (C) * 64 + st_c4); } }

#define STAGE(LA, LB, AR, BR) { _Pragma("unroll") for (int j = 0; j < 8; ++j) { \
        const int row = j * 16 + st_sub; \
        const int idx = row * 64 + (st_c4 ^ ((row & 7) << 3)); \
        s16x4 pa; \
        pa[0] = (short)f2bf(AR[j][0]); pa[1] = (short)f2bf(AR[j][1]); \
        pa[2] = (short)f2bf(AR[j][2]); pa[3] = (short)f2bf(AR[j][3]); \
        *reinterpret_cast<s16x4*>((LA) + idx) = pa; \
        *reinterpret_cast<u32x2*>((LB) + idx) = BR[j]; } }

#define COMPUTE(LA, LB) { _Pragma("unroll") for (int ks = 0; ks < 2; ++ks) { \
        s16x8 a[2], b[8]; \
        _Pragma("unroll") for (int m = 0; m < 2; ++m) { \
            const int row = wid * 32 + m * 16 + lr; \
            const int idx = row * 64 + ((ks * 32 + lg * 8) ^ ((row & 7) << 3)); \
            a[m] = *reinterpret_cast<const s16x8*>((LA) + idx); } \
        _Pragma("unroll") for (int n = 0; n < 8; ++n) { \
            const int out = n * 16 + lr; \
            const int idx = out * 64 + ((ks * 32 + lg * 8) ^ ((out & 7) << 3)); \
            b[n] = *reinterpret_cast<const s16x8*>((LB) + idx); } \
        _Pragma("unroll") for (int n = 0; n < 8; ++n) { \
            acc[0][n] = __builtin_amdgcn_mfma_f32_16x16x32_bf16(a[0], b[n], acc[0][n], 0, 0, 0); \
            acc[1][n] = __builtin_amdgcn_mfma_f32_16x16x32_bf16(a[1], b[n], acc[1][n], 0, 0, 0); } } }

    f32x4 acc[2][8];
#pragma unroll
    for (int m = 0; m < 2; ++m)
#pragma unroll
        for (int n = 0; n < 8; ++n) acc[m][n] = (f32x4)(0.0f);

    // prologue: c0 -> R0, c1 -> R1, stage c0
    LOADA(ar0, 0); LOADB(br0, 0);
    LOADA(ar1, 1); LOADB(br1, 1);
    STAGE(A0, B0, ar0, br0);
    BARRIER_LGKM();
    // phase 1: issue c2 -> R0 (freed), stage c1 from R1, compute c0
    LOADA(ar0, 2); LOADB(br0, 2);
    STAGE(A1, B1, ar1, br1);
    COMPUTE(A0, B0);
    BARRIER_LGKM();
    // phase 2: issue c3 -> R1, stage c2 from R0, compute c1
    LOADA(ar1, 3); LOADB(br1, 3);
    STAGE(A0, B0, ar0, br0);
    COMPUTE(A1, B1);
    BARRIER_LGKM();
    // phase 3: stage c3 from R1, compute c2
    STAGE(A1, B1, ar1, br1);
    COMPUTE(A0, B0);
    BARRIER_LGKM();
    // phase 4: compute c3
    COMPUTE(A1, B1);
    BARRIER_LGKM();   // all LDS reads done before EP overwrites staging LDS

    // epilogue: acc -> EP (padded) -> row-linear 16B dense stores
#pragma unroll
    for (int m = 0; m < 2; ++m) {
#pragma unroll
        for (int n = 0; n < 8; ++n) {
#pragma unroll
            for (int r = 0; r < 4; ++r) {
                const int rl = wid * 32 + m * 16 + lg * 4 + r;
                EP[rl * EW + n * 16 + lr] = f2bf(acc[m][n][r]);
            }
        }
    }
    BARRIER_LGKM();
#pragma unroll
    for (int p = 0; p < 8; ++p) {
        const int rl  = p * 16 + (tid >> 4);
        const int ch0 = (tid & 15) * 8;
        const int row = row0 + rl;
        if (row < NODES) {
            const s16x8 v = *reinterpret_cast<const s16x8*>(EP + rl * EW + ch0);
            const long sb = (long)(ch0 >> 6) * ((long)SROW * SLICE_CH);
            *reinterpret_cast<s16x8*>(h_s + sb + (long)row * SLICE_CH + (ch0 & 63)) = v;
        }
    }
#undef LOADA
#undef LOADB
#undef STAGE
#undef COMPUTE
}

// ---------------- Aggregation: 2 slices x 64ch, XCD-quad affine -------------
// (unchanged: ~41us, near the L3-serve floor: E x 256B logical gather =
// 410MB at L3 BW + 51MB out writes; FETCH == compulsory since R5.)
__global__ __launch_bounds__(320) void gcn_agg(const int* __restrict__ ptr,
                                               const int* __restrict__ idx,
                                               const unsigned short* __restrict__ h_s,
                                               const float* __restrict__ inv_deg,
                                               float* __restrict__ out, int E) {
    const int lane  = threadIdx.x & 63;
    const int wid   = threadIdx.x >> 6;               // 0..4
    const int q     = blockIdx.x & 7;                 // XCD id
    const int slice = q >> 2;                         // 0..1
    const int chunk = (blockIdx.x >> 3) * 4 + (q & 3);  // 0..2499
    const int g     = lane >> 3;                      // node sub-index 0..7
    const int c     = lane & 7;                       // eighth-row 0..7
    const int node  = chunk * 40 + wid * 8 + g;       // 2500*40 = 100000

    const int p0  = ptr[node];
    const int deg = ptr[node + 1] - p0;
    const int Em1 = E - 1;
    const float w = inv_deg[node];

    // preload edge indices: lane c holds edges {c, c+8, c+16, c+24} of node g
    int r[4];
#pragma unroll
    for (int j = 0; j < 4; ++j) {
        int a = p0 + c + 8 * j;
        a = a < Em1 ? a : Em1;
        r[j] = idx[a];
    }

    const unsigned short* hb = h_s + (long)slice * ((long)SROW * SLICE_CH) + c * 8;

    float acc[8];
#pragma unroll
    for (int t = 0; t < 8; ++t) acc[t] = 0.0f;

#pragma unroll
    for (int e = 0; e < 32; ++e) {
        // edge e of node g is held by lane g*8 + (e&7), register e>>3
        int s = __shfl(r[e >> 3], (lane & 56) | (e & 7));
        s = e < deg ? s : NODES;                      // zero row: no predication
        const u32x4 v = *reinterpret_cast<const u32x4*>(hb + (long)s * SLICE_CH);
        acc[0] += lo2f(v[0]); acc[1] += hi2f(v[0]);
        acc[2] += lo2f(v[1]); acc[3] += hi2f(v[1]);
        acc[4] += lo2f(v[2]); acc[5] += hi2f(v[2]);
        acc[6] += lo2f(v[3]); acc[7] += hi2f(v[3]);
    }

    float* op = out + (long)node * DOUT + slice * SLICE_CH + c * 8;
    f32x4 o0, o1;
    o0[0] = acc[0] * w; o0[1] = acc[1] * w; o0[2] = acc[2] * w; o0[3] = acc[3] * w;
    o1[0] = acc[4] * w; o1[1] = acc[5] * w; o1[2] = acc[6] * w; o1[3] = acc[7] * w;
    *reinterpret_cast<f32x4*>(op) = o0;
    *reinterpret_cast<f32x4*>(op + 4) = o1;
}

extern "C" void kernel_launch(void* const* d_in, const int* in_sizes, int n_in,
                              void* d_out, int out_size, void* d_ws, size_t ws_size,
                              hipStream_t stream) {
    const float* x   = (const float*)d_in[0];
    const float* W   = (const float*)d_in[1];
    const int*   ptr = (const int*)d_in[2];
    const int*   idx = (const int*)d_in[3];
    // d_in[4] (dst) unused: CSR ptr encodes destinations.
    float* out = (float*)d_out;
    const int E = in_sizes[3];

    char* ws = (char*)d_ws;
    unsigned short* wsW     = (unsigned short*)ws;               // 64 KB
    float*          inv_deg = (float*)(ws + (64 << 10));         // 400 KB
    unsigned short* h_s     = (unsigned short*)(ws + (1 << 20)); // 2*SROW*64*2B

    gcn_prep<<<391, 256, 0, stream>>>(W, ptr, wsW, inv_deg, h_s);
    // 782 blocks x (128x128) tile; 4 waves/block, dbuf LDS, lgkm-only barriers
    gcn_gemm<<<782, 256, 0, stream>>>(x, wsW, h_s);
    // 625 x 8 blocks: XCD q=blockIdx&7 -> slice q>>2, chunk=(blockIdx>>3)*4+(q&3)
    gcn_agg<<<5000, 320, 0, stream>>>(ptr, idx, h_s, inv_deg, out, E);
}